// Round 2
// baseline (55.927 us; speedup 1.0000x reference)
//
#include <hip/hip_runtime.h>
#include <math.h>

#define NM  512   // N_MODES
#define KTH 511   // number of thetas = N_MODES - 1

// Closed form of the beam-splitter cascade applied to I (row-major U):
//   U[r][j] = 0                                  for j > r+1
//   U[r][r+1] = s_r                              (r <= 510)
//   U[r][j]   = c_{j-1} * c_r * prod_{t=j}^{r-1} (-s_t)   for 1 <= j <= r
//   U[r][0]   =           c_r * prod_{t=0}^{r-1} (-s_t)
// (c_511 := 1 since there is no theta_511.)
// Product magnitude via exp(LP[r]-LP[j]), LP = prefix sum of log|s_t|;
// sign via parity prefix of negative factors. Underflow -> 0 gracefully,
// matching the reference's own float32 product decay.

// Workspace layout (floats): c[512] | s[512] | LP[512] | NEG[512] (as int)

__global__ __launch_bounds__(512) void setup_tables(const float* __restrict__ thetas,
                                                    float* __restrict__ ws) {
    const int i = threadIdx.x;            // 0..511
    float*  c   = ws;
    float*  s   = ws + NM;
    float*  LP  = ws + 2 * NM;
    int*    NEG = (int*)(ws + 3 * NM);

    float sv = 0.0f, cv = 1.0f;
    if (i < KTH) {
        const float th = thetas[i];
        sv = sinf(th);
        cv = cosf(th);
    }
    c[i] = cv;
    s[i] = sv;

    // per-theta log-magnitude and sign of (-s_i)
    float a   = (i < KTH) ? logf(fabsf(sv)) : 0.0f;
    int   neg = (i < KTH) ? (sv > 0.0f ? 1 : 0) : 0;   // (-s) < 0 iff s > 0

    __shared__ float la[NM];
    __shared__ int   na[NM];
    la[i] = a;
    na[i] = neg;
    __syncthreads();

    // inclusive Hillis-Steele scan over 512 entries
    #pragma unroll
    for (int off = 1; off < NM; off <<= 1) {
        float tf = (i >= off) ? la[i - off] : 0.0f;
        int   ti = (i >= off) ? na[i - off] : 0;
        __syncthreads();
        la[i] += tf;
        na[i] += ti;
        __syncthreads();
    }

    // exclusive prefix: LP[m] = sum_{t<m} log|s_t|, NEG[m] = #neg among t<m
    LP[i]  = (i == 0) ? 0.0f : la[i - 1];
    NEG[i] = (i == 0) ? 0    : na[i - 1];
}

__global__ __launch_bounds__(256) void fill_unitary(const float* __restrict__ ws,
                                                    float* __restrict__ U) {
    const float* c   = ws;
    const float* s   = ws + NM;
    const float* LP  = ws + 2 * NM;
    const int*   NEG = (const int*)(ws + 3 * NM);

    const int idx = blockIdx.x * 256 + threadIdx.x;   // 0 .. 512*512-1
    const int r   = idx >> 9;
    const int j   = idx & (NM - 1);

    float out;
    if (j > r + 1) {
        out = 0.0f;
    } else if (j == r + 1) {
        out = s[r];
    } else {                                          // j <= r
        const float cj  = (j == 0) ? 1.0f : c[j - 1];
        const float mag = __expf(LP[r] - LP[j]) * cj * c[r];
        const int   par = (NEG[r] - NEG[j]) & 1;
        out = par ? -mag : mag;
    }
    U[idx] = out;
}

extern "C" void kernel_launch(void* const* d_in, const int* in_sizes, int n_in,
                              void* d_out, int out_size, void* d_ws, size_t ws_size,
                              hipStream_t stream) {
    const float* thetas = (const float*)d_in[0];
    float*       U      = (float*)d_out;
    float*       ws     = (float*)d_ws;

    setup_tables<<<1, NM, 0, stream>>>(thetas, ws);
    fill_unitary<<<(NM * NM) / 256, 256, 0, stream>>>(ws, U);
}